// Round 19
// baseline (397.163 us; speedup 1.0000x reference)
//
#include <hip/hip_runtime.h>
#include <math.h>

#define DD 128
#define HH 256

typedef __attribute__((ext_vector_type(8))) short bf16x8;
typedef __attribute__((ext_vector_type(4))) float f32x4;
typedef __attribute__((ext_vector_type(2))) float f32x2;
typedef unsigned short u16;
typedef unsigned int u32;
typedef unsigned long long u64;
typedef unsigned char u8;

__device__ __forceinline__ float bf2f(u16 u) {
  union { u32 i; float f; } v; v.i = ((u32)u) << 16; return v.f;
}
__device__ __forceinline__ u16 f2bf(float f) {
  union { u32 i; float f; } v; v.f = f;
  u32 r = v.i + 0x7FFFu + ((v.i >> 16) & 1u);
  return (u16)(r >> 16);
}

// ====== mergeA: transpose_all (512) | g3 (1) | degree count + posrec (512) ======
#define GA_T 512
#define GA_C 512
__global__ __launch_bounds__(256) void mergeA(
    const float* __restrict__ W1a, const float* __restrict__ W1b,
    const float* __restrict__ W2a, const float* __restrict__ W2b,
    u16* __restrict__ o1, u16* __restrict__ o2,
    u16* __restrict__ o3, u16* __restrict__ o4,
    const float* __restrict__ gf,
    const float* __restrict__ W3a, const float* __restrict__ b3a,
    const float* __restrict__ W3b, const float* __restrict__ b3b,
    float* __restrict__ g3out,
    const int* __restrict__ eix, u32* __restrict__ deg,
    u32* __restrict__ posrec, int twoE) {
  const int b = blockIdx.x;
  if (b < GA_T) {
    int idx = b * 256 + threadIdx.x;   // 4*DD*HH = 512*256 exactly
    int m = idx >> 15;
    int r = idx & 32767;
    const float* in; u16* out; int K, Nc;
    if (m == 0)      { in = W1a; out = o1; K = DD; Nc = HH; }
    else if (m == 1) { in = W1b; out = o2; K = HH; Nc = DD; }
    else if (m == 2) { in = W2a; out = o3; K = DD; Nc = HH; }
    else             { in = W2b; out = o4; K = HH; Nc = DD; }
    int k = r / Nc, n = r % Nc;
    out[n * K + k] = f2bf(in[r]);
  } else if (b == GA_T) {
    __shared__ float gs[DD];
    __shared__ float hs[HH];
    int t = threadIdx.x;
    if (t < DD) gs[t] = gf[t];
    __syncthreads();
    float acc = b3a[t];
    for (int k = 0; k < DD; ++k) acc = fmaf(gs[k], W3a[k * HH + t], acc);
    hs[t] = acc > 0.f ? acc : 0.f;
    __syncthreads();
    if (t < DD) {
      float o = b3b[t];
      for (int j = 0; j < HH; ++j) o = fmaf(hs[j], W3b[j * DD + t], o);
      g3out[t] = o;
    }
  } else {
    int t = (b - GA_T - 1) * 256 + threadIdx.x;
    const int stride = GA_C * 256;
    for (; t < twoE; t += stride) posrec[t] = atomicAdd(&deg[eix[t]], 1u);
  }
}

// ====== gemm_l1 (2048 blocks) | 4-wave scan (1 block; l1 never reads rowstart) ======
#define L1_GEMM 2048
__global__ __launch_bounds__(256) void gemm_l1_scan(const float* __restrict__ x,
    const u16* __restrict__ w1aT, const float* __restrict__ b1a,
    const u16* __restrict__ w2aT, const float* __restrict__ b2a,
    u16* __restrict__ hid, int M,
    const u32* __restrict__ deg, u32* __restrict__ rowstart, int N) {
  if (blockIdx.x >= L1_GEMM) {
    __shared__ u32 wsum[4];
    const int t = threadIdx.x;
    const int w = t >> 6, lane = t & 63;
    const int span = (((N + 3) >> 2) + 63) & ~63;
    const int bg = w * span;
    const int e = min(bg + span, N);

    u32 s = 0;
    for (int i = bg + lane; i < e; i += 64) s += deg[i];
#pragma unroll
    for (int off = 32; off; off >>= 1) s += __shfl_xor(s, off);
    if (lane == 0) wsum[w] = s;
    __syncthreads();
    u32 carry = 0;
    for (int i = 0; i < w; ++i) carry += wsum[i];
    for (int i0 = bg; i0 < e; i0 += 64) {
      int i = i0 + lane;
      u32 v = (i < e) ? deg[i] : 0u;
      u32 inc = v;
#pragma unroll
      for (int off = 1; off < 64; off <<= 1) {
        u32 u2 = __shfl_up(inc, off);
        if (lane >= off) inc += u2;
      }
      u32 excl = carry + inc - v;
      if (i < e) rowstart[i] = excl;
      carry += __shfl(inc, 63);
    }
    if (w == 3 && lane == 63) rowstart[N] = carry;
    return;
  }
  const int wave = (blockIdx.x * 256 + threadIdx.x) >> 6;
  const int lane = threadIdx.x & 63;
  const int totalWaves = L1_GEMM * 4;
  const int nc = wave & 7;
  const int mw = wave >> 3;
  const int mStride = totalWaves >> 3;
  const int which = nc >> 2;
  const int c0 = (nc & 3) * 64;
  const u16* wT = which ? w2aT : w1aT;
  const float* bs = which ? b2a : b1a;
  const int l15 = lane & 15, l4 = lane >> 4;

  bf16x8 bfrag[4][4];
  float bcol[4];
#pragma unroll
  for (int t = 0; t < 4; ++t) {
    const int col = c0 + t * 16 + l15;
    const u16* bb = wT + (size_t)col * DD + l4 * 8;
#pragma unroll
    for (int kb = 0; kb < 4; ++kb) bfrag[kb][t] = *(const bf16x8*)(bb + kb * 32);
    bcol[t] = bs[col];
  }

  const int mTiles = (M + 15) >> 4;
  for (int mt = mw; mt < mTiles; mt += mStride) {
    const int m0 = mt << 4;
    int rowA = m0 + l15; if (rowA >= M) rowA = M - 1;
    const float* xr = x + (size_t)rowA * DD + l4 * 8;
    bf16x8 ax[4];
#pragma unroll
    for (int kb = 0; kb < 4; ++kb) {
      f32x4 a = *(const f32x4*)(xr + kb * 32);
      f32x4 b = *(const f32x4*)(xr + kb * 32 + 4);
      bf16x8 v;
      v[0] = (short)f2bf(a.x); v[1] = (short)f2bf(a.y);
      v[2] = (short)f2bf(a.z); v[3] = (short)f2bf(a.w);
      v[4] = (short)f2bf(b.x); v[5] = (short)f2bf(b.y);
      v[6] = (short)f2bf(b.z); v[7] = (short)f2bf(b.w);
      ax[kb] = v;
    }
    f32x4 acc[4] = {{0,0,0,0},{0,0,0,0},{0,0,0,0},{0,0,0,0}};
#pragma unroll
    for (int kb = 0; kb < 4; ++kb)
#pragma unroll
      for (int t = 0; t < 4; ++t)
        acc[t] = __builtin_amdgcn_mfma_f32_16x16x32_bf16(ax[kb], bfrag[kb][t], acc[t], 0, 0, 0);
#pragma unroll
    for (int t = 0; t < 4; ++t)
#pragma unroll
      for (int r = 0; r < 4; ++r) {
        const int row = m0 + l4 * 4 + r;
        float v = acc[t][r] + bcol[t];
        v = v > 0.f ? v : 0.f;
        if (row < M) hid[(size_t)row * 512 + which * 256 + c0 + t * 16 + l15] = f2bf(v);
      }
  }
}

// ====== gemm_l2 (2048) | atomic-free scatter (512, in l2's tail; rowstart ready) ======
#define L2_GEMM 2048
#define L2_SCAT 512
__global__ __launch_bounds__(256) void gemm_l2_scat(const u16* __restrict__ hid,
    const u16* __restrict__ w1bT, const float* __restrict__ b1b,
    const u16* __restrict__ w2bT, const float* __restrict__ b2b,
    u16* __restrict__ h1, u8* __restrict__ h28, int M,
    const int* __restrict__ eix, const u32* __restrict__ rowstart,
    const u32* __restrict__ posrec, uint2* __restrict__ adj, int E) {
  if (blockIdx.x >= L2_GEMM) {
    int t = (blockIdx.x - L2_GEMM) * 256 + threadIdx.x;
    const int stride = L2_SCAT * 256;
    const int twoE = 2 * E;
    for (; t < twoE; t += stride) {
      int node, eid, other;
      if (t < E) { node = eix[t]; eid = t;     other = eix[t + E]; }
      else       { node = eix[t]; eid = t - E; other = eix[t - E]; }
      adj[rowstart[node] + posrec[t]] = make_uint2((u32)eid, (u32)other);
    }
    return;
  }
  const int wave = (blockIdx.x * 256 + threadIdx.x) >> 6;
  const int lane = threadIdx.x & 63;
  const int totalWaves = L2_GEMM * 4;
  const int nc = wave & 3;
  const int mw = wave >> 2;
  const int mStride = totalWaves >> 2;
  const int which = nc >> 1;
  const int c0 = (nc & 1) * 64;
  const u16* wT = which ? w2bT : w1bT;
  const float* bs = which ? b2b : b1b;
  const int l15 = lane & 15, l4 = lane >> 4;

  bf16x8 bfrag[8][4];
  float bcol[4];
#pragma unroll
  for (int t = 0; t < 4; ++t) {
    const int col = c0 + t * 16 + l15;
    const u16* bb = wT + (size_t)col * HH + l4 * 8;
#pragma unroll
    for (int kb = 0; kb < 8; ++kb) bfrag[kb][t] = *(const bf16x8*)(bb + kb * 32);
    bcol[t] = bs[col];
  }

  const int mTiles = (M + 15) >> 4;
  for (int mt = mw; mt < mTiles; mt += mStride) {
    const int m0 = mt << 4;
    int rowA = m0 + l15; if (rowA >= M) rowA = M - 1;
    const u16* arow = hid + (size_t)rowA * 512 + which * 256 + l4 * 8;
    f32x4 acc[4] = {{0,0,0,0},{0,0,0,0},{0,0,0,0},{0,0,0,0}};
#pragma unroll
    for (int kb = 0; kb < 8; ++kb) {
      bf16x8 afrag = *(const bf16x8*)(arow + kb * 32);
#pragma unroll
      for (int t = 0; t < 4; ++t)
        acc[t] = __builtin_amdgcn_mfma_f32_16x16x32_bf16(afrag, bfrag[kb][t], acc[t], 0, 0, 0);
    }
#pragma unroll
    for (int t = 0; t < 4; ++t)
#pragma unroll
      for (int r = 0; r < 4; ++r) {
        const int row = m0 + l4 * 4 + r;
        if (row >= M) continue;
        float v = acc[t][r] + bcol[t];
        const int col = c0 + t * 16 + l15;
        if (which) {
          u32 w = (u32)__builtin_amdgcn_cvt_pk_fp8_f32(v, v, 0, false);
          h28[(size_t)row * DD + col] = (u8)(w & 0xffu);
        } else {
          h1[(size_t)row * DD + col] = f2bf(v);
        }
      }
  }
}

// ====== sigmoid -> fp8 (pure streamer, immediately before gather: s8 L3-hot) ======
__global__ __launch_bounds__(256) void sigmoid_fp8(const float* __restrict__ ef,
                                                   uint2* __restrict__ s8, int n8) {
  int i = blockIdx.x * 256 + threadIdx.x;
  const int stride = gridDim.x * 256;
  for (; i < n8; i += stride) {
    const f32x4 a = __builtin_nontemporal_load(((const f32x4*)ef) + i * 2);
    const f32x4 bb = __builtin_nontemporal_load(((const f32x4*)ef) + i * 2 + 1);
    float s0 = 1.f / (1.f + __expf(-a.x));
    float s1 = 1.f / (1.f + __expf(-a.y));
    float s2 = 1.f / (1.f + __expf(-a.z));
    float s3 = 1.f / (1.f + __expf(-a.w));
    float s4 = 1.f / (1.f + __expf(-bb.x));
    float s5 = 1.f / (1.f + __expf(-bb.y));
    float s6 = 1.f / (1.f + __expf(-bb.z));
    float s7 = 1.f / (1.f + __expf(-bb.w));
    u32 w0 = (u32)__builtin_amdgcn_cvt_pk_fp8_f32(s0, s1, 0, false);
    w0 = (u32)__builtin_amdgcn_cvt_pk_fp8_f32(s2, s3, (int)w0, true);
    u32 w1 = (u32)__builtin_amdgcn_cvt_pk_fp8_f32(s4, s5, 0, false);
    w1 = (u32)__builtin_amdgcn_cvt_pk_fp8_f32(s6, s7, (int)w1, true);
    s8[i] = make_uint2(w0, w1);
  }
}

// ====== gather from fp8 s8/h28: wave-per-row, 16-deep batched ======
__device__ __forceinline__ void acc_fp8(u32 sv, u32 hv, float& dx, float& dy,
                                        float& ax, float& ay) {
  f32x2 sf = __builtin_amdgcn_cvt_pk_f32_fp8((int)sv, false);
  f32x2 hf = __builtin_amdgcn_cvt_pk_f32_fp8((int)hv, false);
  dx += sf.x; dy += sf.y;
  ax = fmaf(sf.x, hf.x, ax);
  ay = fmaf(sf.y, hf.y, ay);
}

__global__ __launch_bounds__(256) void gather_fp8(const float* __restrict__ x,
    const u16* __restrict__ h1, const u8* __restrict__ h28,
    const u8* __restrict__ s8, const u64* __restrict__ adj,
    const u32* __restrict__ rowstart, const float* __restrict__ g3,
    float* __restrict__ out, int N) {
  int row0 = (blockIdx.x * 256 + threadIdx.x) >> 6;
  if (row0 >= N) return;
  const int row = __builtin_amdgcn_readfirstlane(row0);
  const int lane = threadIdx.x & 63;
  const int d0 = lane * 2;

  const u32 beg = rowstart[row];
  const u32 end = rowstart[row + 1];

  // hoist row-local loads: their latency hides under the edge loop
  const size_t base = (size_t)row * DD + d0;
  f32x2 xv = __builtin_nontemporal_load((const f32x2*)(x + base));
  u32 h1u = __builtin_nontemporal_load((const u32*)(h1 + base));
  f32x2 gv = *(const f32x2*)(g3 + d0);

  float dx = 0.f, dy = 0.f, ax = 0.f, ay = 0.f;
  u32 j = beg;
  for (; j + 16 <= end; j += 16) {
    u64 e[16];
    u32 sv[16], hv[16];
#pragma unroll
    for (int q = 0; q < 16; ++q) e[q] = __builtin_nontemporal_load(adj + j + q);
#pragma unroll
    for (int q = 0; q < 16; ++q) {
      sv[q] = *(const u16*)(s8  + (size_t)(u32)e[q] * DD + d0);
      hv[q] = *(const u16*)(h28 + (size_t)(u32)(e[q] >> 32) * DD + d0);
    }
#pragma unroll
    for (int q = 0; q < 16; ++q) acc_fp8(sv[q], hv[q], dx, dy, ax, ay);
  }
  for (; j + 4 <= end; j += 4) {
    u64 e[4];
    u32 sv[4], hv[4];
#pragma unroll
    for (int q = 0; q < 4; ++q) e[q] = __builtin_nontemporal_load(adj + j + q);
#pragma unroll
    for (int q = 0; q < 4; ++q) {
      sv[q] = *(const u16*)(s8  + (size_t)(u32)e[q] * DD + d0);
      hv[q] = *(const u16*)(h28 + (size_t)(u32)(e[q] >> 32) * DD + d0);
    }
#pragma unroll
    for (int q = 0; q < 4; ++q) acc_fp8(sv[q], hv[q], dx, dy, ax, ay);
  }
  for (; j < end; ++j) {
    u64 e = __builtin_nontemporal_load(adj + j);
    u32 sv = *(const u16*)(s8  + (size_t)(u32)e * DD + d0);
    u32 hv = *(const u16*)(h28 + (size_t)(u32)(e >> 32) * DD + d0);
    acc_fp8(sv, hv, dx, dy, ax, ay);
  }

  float i0 = bf2f((u16)(h1u & 0xffffu)) + ax / (dx + 1e-7f) + gv.x;
  float i1 = bf2f((u16)(h1u >> 16)) + ay / (dy + 1e-7f) + gv.y;

  float s = i0 + i1;
  float q = i0 * i0 + i1 * i1;
#pragma unroll
  for (int off = 32; off; off >>= 1) {
    s += __shfl_xor(s, off);
    q += __shfl_xor(q, off);
  }
  float mean = s * (1.f / 128.f);
  float var = q * (1.f / 128.f) - mean * mean;
  float rstd = rsqrtf(var + 1e-5f);
  float n0v = (i0 - mean) * rstd;
  float n1v = (i1 - mean) * rstd;
  f32x2 ov;
  ov.x = xv.x + (n0v > 0.f ? n0v : 0.f);
  ov.y = xv.y + (n1v > 0.f ? n1v : 0.f);
  __builtin_nontemporal_store(ov, (f32x2*)(out + base));
}

extern "C" void kernel_launch(void* const* d_in, const int* in_sizes, int n_in,
                              void* d_out, int out_size, void* d_ws, size_t ws_size,
                              hipStream_t stream) {
  const float* x   = (const float*)d_in[0];
  const int*   eix = (const int*)d_in[1];
  const float* ef  = (const float*)d_in[2];
  const float* gf  = (const float*)d_in[3];
  const float* W1a = (const float*)d_in[4];
  const float* b1a = (const float*)d_in[5];
  const float* W1b = (const float*)d_in[6];
  const float* b1b = (const float*)d_in[7];
  const float* W2a = (const float*)d_in[8];
  const float* b2a = (const float*)d_in[9];
  const float* W2b = (const float*)d_in[10];
  const float* b2b = (const float*)d_in[11];
  const float* W3a = (const float*)d_in[12];
  const float* b3a = (const float*)d_in[13];
  const float* W3b = (const float*)d_in[14];
  const float* b3b = (const float*)d_in[15];

  const int N = in_sizes[0] / DD;
  const int E = in_sizes[2] / DD;

  char* p = (char*)d_ws;
  auto take = [&](size_t bytes) -> char* {
    char* r = p;
    p += (bytes + 255) & ~(size_t)255;
    return r;
  };
  u16* w1aT   = (u16*)take((size_t)DD * HH * 2);
  u16* w1bT   = (u16*)take((size_t)DD * HH * 2);
  u16* w2aT   = (u16*)take((size_t)DD * HH * 2);
  u16* w2bT   = (u16*)take((size_t)DD * HH * 2);
  u16* hidb   = (u16*)take((size_t)N * 512 * 2);
  u16* h1b    = (u16*)take((size_t)N * DD * 2);
  u32* deg    = (u32*)take((size_t)N * 4);
  u32* rowst  = (u32*)take((size_t)(N + 1) * 4);
  u32* posrec = (u32*)take((size_t)2 * E * 4);
  float* g3   = (float*)take((size_t)DD * 4);
  uint2* adj  = (uint2*)take((size_t)2 * E * 8);
  u8* s8      = (u8*)take((size_t)E * DD);      // 77 MB fp8 (L3-resident at gather)
  u8* h28     = (u8*)take((size_t)N * DD);      // 6.4 MB fp8

  hipMemsetAsync(deg, 0, (size_t)N * 4, stream);

  // transposes | g3 | count+posrec
  mergeA<<<GA_T + 1 + GA_C, 256, 0, stream>>>(W1a, W1b, W2a, W2b,
                                              w1aT, w1bT, w2aT, w2bT,
                                              gf, W3a, b3a, W3b, b3b, g3,
                                              eix, deg, posrec, 2 * E);

  // GEMM layer1 | 4-wave scan (l1 never reads rowstart)
  gemm_l1_scan<<<L1_GEMM + 1, 256, 0, stream>>>(x, w1aT, b1a, w2aT, b2a, hidb, N,
                                                deg, rowst, N);
  // GEMM layer2 | atomic-free scatter (rowstart ready after l1 kernel)
  gemm_l2_scat<<<L2_GEMM + L2_SCAT, 256, 0, stream>>>(hidb, w1bT, b1b, w2bT, b2b,
                                                      h1b, h28, N,
                                                      eix, rowst, posrec, adj, E);

  // sigmoid stream LAST before gather — s8 must be L3-hot (R18 lesson)
  sigmoid_fp8<<<4096, 256, 0, stream>>>(ef, (uint2*)s8, E * DD / 8);

  gather_fp8<<<(N + 3) / 4, 256, 0, stream>>>(x, h1b, h28, s8, (const u64*)adj,
                                              rowst, g3, (float*)d_out, N);
}

// Round 20
// 339.318 us; speedup vs baseline: 1.1705x; 1.1705x over previous
//
#include <hip/hip_runtime.h>
#include <math.h>

#define DD 128
#define HH 256

typedef __attribute__((ext_vector_type(8))) short bf16x8;
typedef __attribute__((ext_vector_type(4))) float f32x4;
typedef __attribute__((ext_vector_type(2))) float f32x2;
typedef unsigned short u16;
typedef unsigned int u32;
typedef unsigned long long u64;
typedef unsigned char u8;

__device__ __forceinline__ float bf2f(u16 u) {
  union { u32 i; float f; } v; v.i = ((u32)u) << 16; return v.f;
}
__device__ __forceinline__ u16 f2bf(float f) {
  union { u32 i; float f; } v; v.f = f;
  u32 r = v.i + 0x7FFFu + ((v.i >> 16) & 1u);
  return (u16)(r >> 16);
}

// ====== mergeA: transpose_all (512) | g3 (1) | degree count + posrec (512) ======
#define GA_T 512
#define GA_C 512
__global__ __launch_bounds__(256) void mergeA(
    const float* __restrict__ W1a, const float* __restrict__ W1b,
    const float* __restrict__ W2a, const float* __restrict__ W2b,
    u16* __restrict__ o1, u16* __restrict__ o2,
    u16* __restrict__ o3, u16* __restrict__ o4,
    const float* __restrict__ gf,
    const float* __restrict__ W3a, const float* __restrict__ b3a,
    const float* __restrict__ W3b, const float* __restrict__ b3b,
    float* __restrict__ g3out,
    const int* __restrict__ eix, u32* __restrict__ deg,
    u32* __restrict__ posrec, int twoE) {
  const int b = blockIdx.x;
  if (b < GA_T) {
    int idx = b * 256 + threadIdx.x;   // 4*DD*HH = 512*256 exactly
    int m = idx >> 15;
    int r = idx & 32767;
    const float* in; u16* out; int K, Nc;
    if (m == 0)      { in = W1a; out = o1; K = DD; Nc = HH; }
    else if (m == 1) { in = W1b; out = o2; K = HH; Nc = DD; }
    else if (m == 2) { in = W2a; out = o3; K = DD; Nc = HH; }
    else             { in = W2b; out = o4; K = HH; Nc = DD; }
    int k = r / Nc, n = r % Nc;
    out[n * K + k] = f2bf(in[r]);
  } else if (b == GA_T) {
    __shared__ float gs[DD];
    __shared__ float hs[HH];
    int t = threadIdx.x;
    if (t < DD) gs[t] = gf[t];
    __syncthreads();
    float acc = b3a[t];
    for (int k = 0; k < DD; ++k) acc = fmaf(gs[k], W3a[k * HH + t], acc);
    hs[t] = acc > 0.f ? acc : 0.f;
    __syncthreads();
    if (t < DD) {
      float o = b3b[t];
      for (int j = 0; j < HH; ++j) o = fmaf(hs[j], W3b[j * DD + t], o);
      g3out[t] = o;
    }
  } else {
    int t = (b - GA_T - 1) * 256 + threadIdx.x;
    const int stride = GA_C * 256;
    for (; t < twoE; t += stride) posrec[t] = atomicAdd(&deg[eix[t]], 1u);
  }
}

// 16-wave coalesced two-pass scan (single block)
__global__ __launch_bounds__(1024) void scan_kernel(const u32* __restrict__ deg,
    u32* __restrict__ rowstart, int N) {
  __shared__ u32 wsum[16];
  const int t = threadIdx.x;
  const int w = t >> 6, lane = t & 63;
  const int span = ((N + 1023) & ~1023) >> 4;
  const int b = w * span;
  const int e = min(b + span, N);

  u32 s = 0;
  for (int i = b + lane; i < e; i += 64) s += deg[i];
#pragma unroll
  for (int off = 32; off; off >>= 1) s += __shfl_xor(s, off);
  if (lane == 0) wsum[w] = s;
  __syncthreads();

  u32 carry = 0;
  for (int i = 0; i < w; ++i) carry += wsum[i];

  for (int i0 = b; i0 < e; i0 += 64) {
    int i = i0 + lane;
    u32 v = (i < e) ? deg[i] : 0u;
    u32 inc = v;
#pragma unroll
    for (int off = 1; off < 64; off <<= 1) {
      u32 u2 = __shfl_up(inc, off);
      if (lane >= off) inc += u2;
    }
    u32 excl = carry + inc - v;
    if (i < e) rowstart[i] = excl;
    carry += __shfl(inc, 63);
  }
  if (w == 15 && lane == 63) rowstart[N] = carry;
}

// ====== gemm_l1 (2048 blocks) | atomic-free scatter (512 blocks, runs in l1's tail) ==
#define L1_GEMM 2048
#define L1_SCAT 512
__global__ __launch_bounds__(256) void gemm_l1_scat(const float* __restrict__ x,
    const u16* __restrict__ w1aT, const float* __restrict__ b1a,
    const u16* __restrict__ w2aT, const float* __restrict__ b2a,
    u16* __restrict__ hid, int M,
    const int* __restrict__ eix, const u32* __restrict__ rowstart,
    const u32* __restrict__ posrec, uint2* __restrict__ adj, int E) {
  if (blockIdx.x >= L1_GEMM) {
    int t = (blockIdx.x - L1_GEMM) * 256 + threadIdx.x;
    const int stride = L1_SCAT * 256;
    const int twoE = 2 * E;
    for (; t < twoE; t += stride) {
      int node, eid, other;
      if (t < E) { node = eix[t]; eid = t;     other = eix[t + E]; }
      else       { node = eix[t]; eid = t - E; other = eix[t - E]; }
      adj[rowstart[node] + posrec[t]] = make_uint2((u32)eid, (u32)other);
    }
    return;
  }
  const int wave = (blockIdx.x * 256 + threadIdx.x) >> 6;
  const int lane = threadIdx.x & 63;
  const int totalWaves = L1_GEMM * 4;
  const int nc = wave & 7;
  const int mw = wave >> 3;
  const int mStride = totalWaves >> 3;
  const int which = nc >> 2;
  const int c0 = (nc & 3) * 64;
  const u16* wT = which ? w2aT : w1aT;
  const float* bs = which ? b2a : b1a;
  const int l15 = lane & 15, l4 = lane >> 4;

  bf16x8 bfrag[4][4];
  float bcol[4];
#pragma unroll
  for (int t = 0; t < 4; ++t) {
    const int col = c0 + t * 16 + l15;
    const u16* bb = wT + (size_t)col * DD + l4 * 8;
#pragma unroll
    for (int kb = 0; kb < 4; ++kb) bfrag[kb][t] = *(const bf16x8*)(bb + kb * 32);
    bcol[t] = bs[col];
  }

  const int mTiles = (M + 15) >> 4;
  for (int mt = mw; mt < mTiles; mt += mStride) {
    const int m0 = mt << 4;
    int rowA = m0 + l15; if (rowA >= M) rowA = M - 1;
    const float* xr = x + (size_t)rowA * DD + l4 * 8;
    bf16x8 ax[4];
#pragma unroll
    for (int kb = 0; kb < 4; ++kb) {
      f32x4 a = *(const f32x4*)(xr + kb * 32);
      f32x4 b = *(const f32x4*)(xr + kb * 32 + 4);
      bf16x8 v;
      v[0] = (short)f2bf(a.x); v[1] = (short)f2bf(a.y);
      v[2] = (short)f2bf(a.z); v[3] = (short)f2bf(a.w);
      v[4] = (short)f2bf(b.x); v[5] = (short)f2bf(b.y);
      v[6] = (short)f2bf(b.z); v[7] = (short)f2bf(b.w);
      ax[kb] = v;
    }
    f32x4 acc[4] = {{0,0,0,0},{0,0,0,0},{0,0,0,0},{0,0,0,0}};
#pragma unroll
    for (int kb = 0; kb < 4; ++kb)
#pragma unroll
      for (int t = 0; t < 4; ++t)
        acc[t] = __builtin_amdgcn_mfma_f32_16x16x32_bf16(ax[kb], bfrag[kb][t], acc[t], 0, 0, 0);
#pragma unroll
    for (int t = 0; t < 4; ++t)
#pragma unroll
      for (int r = 0; r < 4; ++r) {
        const int row = m0 + l4 * 4 + r;
        float v = acc[t][r] + bcol[t];
        v = v > 0.f ? v : 0.f;
        if (row < M) hid[(size_t)row * 512 + which * 256 + c0 + t * 16 + l15] = f2bf(v);
      }
  }
}

// Layer 2 of BOTH FCNNs: h1 (bf16) ; h28 (fp8 direct store).
__global__ __launch_bounds__(256) void gemm_l2(const u16* __restrict__ hid,
    const u16* __restrict__ w1bT, const float* __restrict__ b1b,
    const u16* __restrict__ w2bT, const float* __restrict__ b2b,
    u16* __restrict__ h1, u8* __restrict__ h28, int M) {
  const int wave = (blockIdx.x * 256 + threadIdx.x) >> 6;
  const int lane = threadIdx.x & 63;
  const int totalWaves = (gridDim.x * 256) >> 6;
  const int nc = wave & 3;
  const int mw = wave >> 2;
  const int mStride = totalWaves >> 2;
  const int which = nc >> 1;
  const int c0 = (nc & 1) * 64;
  const u16* wT = which ? w2bT : w1bT;
  const float* bs = which ? b2b : b1b;
  const int l15 = lane & 15, l4 = lane >> 4;

  bf16x8 bfrag[8][4];
  float bcol[4];
#pragma unroll
  for (int t = 0; t < 4; ++t) {
    const int col = c0 + t * 16 + l15;
    const u16* bb = wT + (size_t)col * HH + l4 * 8;
#pragma unroll
    for (int kb = 0; kb < 8; ++kb) bfrag[kb][t] = *(const bf16x8*)(bb + kb * 32);
    bcol[t] = bs[col];
  }

  const int mTiles = (M + 15) >> 4;
  for (int mt = mw; mt < mTiles; mt += mStride) {
    const int m0 = mt << 4;
    int rowA = m0 + l15; if (rowA >= M) rowA = M - 1;
    const u16* arow = hid + (size_t)rowA * 512 + which * 256 + l4 * 8;
    f32x4 acc[4] = {{0,0,0,0},{0,0,0,0},{0,0,0,0},{0,0,0,0}};
#pragma unroll
    for (int kb = 0; kb < 8; ++kb) {
      bf16x8 afrag = *(const bf16x8*)(arow + kb * 32);
#pragma unroll
      for (int t = 0; t < 4; ++t)
        acc[t] = __builtin_amdgcn_mfma_f32_16x16x32_bf16(afrag, bfrag[kb][t], acc[t], 0, 0, 0);
    }
#pragma unroll
    for (int t = 0; t < 4; ++t)
#pragma unroll
      for (int r = 0; r < 4; ++r) {
        const int row = m0 + l4 * 4 + r;
        if (row >= M) continue;
        float v = acc[t][r] + bcol[t];
        const int col = c0 + t * 16 + l15;
        if (which) {
          u32 w = (u32)__builtin_amdgcn_cvt_pk_fp8_f32(v, v, 0, false);
          h28[(size_t)row * DD + col] = (u8)(w & 0xffu);
        } else {
          h1[(size_t)row * DD + col] = f2bf(v);
        }
      }
  }
}

// ====== sigmoid -> fp8 (pure streamer, immediately before gather: s8 L3-hot) ======
__global__ __launch_bounds__(256) void sigmoid_fp8(const float* __restrict__ ef,
                                                   uint2* __restrict__ s8, int n8) {
  int i = blockIdx.x * 256 + threadIdx.x;
  const int stride = gridDim.x * 256;
  for (; i < n8; i += stride) {
    const f32x4 a = __builtin_nontemporal_load(((const f32x4*)ef) + i * 2);
    const f32x4 bb = __builtin_nontemporal_load(((const f32x4*)ef) + i * 2 + 1);
    float s0 = 1.f / (1.f + __expf(-a.x));
    float s1 = 1.f / (1.f + __expf(-a.y));
    float s2 = 1.f / (1.f + __expf(-a.z));
    float s3 = 1.f / (1.f + __expf(-a.w));
    float s4 = 1.f / (1.f + __expf(-bb.x));
    float s5 = 1.f / (1.f + __expf(-bb.y));
    float s6 = 1.f / (1.f + __expf(-bb.z));
    float s7 = 1.f / (1.f + __expf(-bb.w));
    u32 w0 = (u32)__builtin_amdgcn_cvt_pk_fp8_f32(s0, s1, 0, false);
    w0 = (u32)__builtin_amdgcn_cvt_pk_fp8_f32(s2, s3, (int)w0, true);
    u32 w1 = (u32)__builtin_amdgcn_cvt_pk_fp8_f32(s4, s5, 0, false);
    w1 = (u32)__builtin_amdgcn_cvt_pk_fp8_f32(s6, s7, (int)w1, true);
    s8[i] = make_uint2(w0, w1);
  }
}

// ====== gather from fp8 s8/h28: wave-per-row, 16-deep batched ======
__device__ __forceinline__ void acc_fp8(u32 sv, u32 hv, float& dx, float& dy,
                                        float& ax, float& ay) {
  f32x2 sf = __builtin_amdgcn_cvt_pk_f32_fp8((int)sv, false);
  f32x2 hf = __builtin_amdgcn_cvt_pk_f32_fp8((int)hv, false);
  dx += sf.x; dy += sf.y;
  ax = fmaf(sf.x, hf.x, ax);
  ay = fmaf(sf.y, hf.y, ay);
}

__global__ __launch_bounds__(256) void gather_fp8(const float* __restrict__ x,
    const u16* __restrict__ h1, const u8* __restrict__ h28,
    const u8* __restrict__ s8, const u64* __restrict__ adj,
    const u32* __restrict__ rowstart, const float* __restrict__ g3,
    float* __restrict__ out, int N) {
  int row0 = (blockIdx.x * 256 + threadIdx.x) >> 6;
  if (row0 >= N) return;
  const int row = __builtin_amdgcn_readfirstlane(row0);
  const int lane = threadIdx.x & 63;
  const int d0 = lane * 2;

  const u32 beg = rowstart[row];
  const u32 end = rowstart[row + 1];

  float dx = 0.f, dy = 0.f, ax = 0.f, ay = 0.f;
  u32 j = beg;
  for (; j + 16 <= end; j += 16) {
    u64 e[16];
    u32 sv[16], hv[16];
#pragma unroll
    for (int q = 0; q < 16; ++q) e[q] = __builtin_nontemporal_load(adj + j + q);
#pragma unroll
    for (int q = 0; q < 16; ++q) {
      sv[q] = *(const u16*)(s8  + (size_t)(u32)e[q] * DD + d0);
      hv[q] = *(const u16*)(h28 + (size_t)(u32)(e[q] >> 32) * DD + d0);
    }
#pragma unroll
    for (int q = 0; q < 16; ++q) acc_fp8(sv[q], hv[q], dx, dy, ax, ay);
  }
  for (; j + 4 <= end; j += 4) {
    u64 e[4];
    u32 sv[4], hv[4];
#pragma unroll
    for (int q = 0; q < 4; ++q) e[q] = __builtin_nontemporal_load(adj + j + q);
#pragma unroll
    for (int q = 0; q < 4; ++q) {
      sv[q] = *(const u16*)(s8  + (size_t)(u32)e[q] * DD + d0);
      hv[q] = *(const u16*)(h28 + (size_t)(u32)(e[q] >> 32) * DD + d0);
    }
#pragma unroll
    for (int q = 0; q < 4; ++q) acc_fp8(sv[q], hv[q], dx, dy, ax, ay);
  }
  for (; j < end; ++j) {
    u64 e = __builtin_nontemporal_load(adj + j);
    u32 sv = *(const u16*)(s8  + (size_t)(u32)e * DD + d0);
    u32 hv = *(const u16*)(h28 + (size_t)(u32)(e >> 32) * DD + d0);
    acc_fp8(sv, hv, dx, dy, ax, ay);
  }

  const size_t base = (size_t)row * DD + d0;
  f32x2 xv = __builtin_nontemporal_load((const f32x2*)(x + base));
  u32 h1u = __builtin_nontemporal_load((const u32*)(h1 + base));
  f32x2 gv = *(const f32x2*)(g3 + d0);

  float i0 = bf2f((u16)(h1u & 0xffffu)) + ax / (dx + 1e-7f) + gv.x;
  float i1 = bf2f((u16)(h1u >> 16)) + ay / (dy + 1e-7f) + gv.y;

  float s = i0 + i1;
  float q = i0 * i0 + i1 * i1;
#pragma unroll
  for (int off = 32; off; off >>= 1) {
    s += __shfl_xor(s, off);
    q += __shfl_xor(q, off);
  }
  float mean = s * (1.f / 128.f);
  float var = q * (1.f / 128.f) - mean * mean;
  float rstd = rsqrtf(var + 1e-5f);
  float n0v = (i0 - mean) * rstd;
  float n1v = (i1 - mean) * rstd;
  f32x2 ov;
  ov.x = xv.x + (n0v > 0.f ? n0v : 0.f);
  ov.y = xv.y + (n1v > 0.f ? n1v : 0.f);
  __builtin_nontemporal_store(ov, (f32x2*)(out + base));
}

extern "C" void kernel_launch(void* const* d_in, const int* in_sizes, int n_in,
                              void* d_out, int out_size, void* d_ws, size_t ws_size,
                              hipStream_t stream) {
  const float* x   = (const float*)d_in[0];
  const int*   eix = (const int*)d_in[1];
  const float* ef  = (const float*)d_in[2];
  const float* gf  = (const float*)d_in[3];
  const float* W1a = (const float*)d_in[4];
  const float* b1a = (const float*)d_in[5];
  const float* W1b = (const float*)d_in[6];
  const float* b1b = (const float*)d_in[7];
  const float* W2a = (const float*)d_in[8];
  const float* b2a = (const float*)d_in[9];
  const float* W2b = (const float*)d_in[10];
  const float* b2b = (const float*)d_in[11];
  const float* W3a = (const float*)d_in[12];
  const float* b3a = (const float*)d_in[13];
  const float* W3b = (const float*)d_in[14];
  const float* b3b = (const float*)d_in[15];

  const int N = in_sizes[0] / DD;
  const int E = in_sizes[2] / DD;

  char* p = (char*)d_ws;
  auto take = [&](size_t bytes) -> char* {
    char* r = p;
    p += (bytes + 255) & ~(size_t)255;
    return r;
  };
  u16* w1aT   = (u16*)take((size_t)DD * HH * 2);
  u16* w1bT   = (u16*)take((size_t)DD * HH * 2);
  u16* w2aT   = (u16*)take((size_t)DD * HH * 2);
  u16* w2bT   = (u16*)take((size_t)DD * HH * 2);
  u16* hidb   = (u16*)take((size_t)N * 512 * 2);
  u16* h1b    = (u16*)take((size_t)N * DD * 2);
  u32* deg    = (u32*)take((size_t)N * 4);
  u32* rowst  = (u32*)take((size_t)(N + 1) * 4);
  u32* posrec = (u32*)take((size_t)2 * E * 4);
  float* g3   = (float*)take((size_t)DD * 4);
  uint2* adj  = (uint2*)take((size_t)2 * E * 8);
  u8* s8      = (u8*)take((size_t)E * DD);      // 77 MB fp8 (L3-resident at gather)
  u8* h28     = (u8*)take((size_t)N * DD);      // 6.4 MB fp8

  hipMemsetAsync(deg, 0, (size_t)N * 4, stream);

  // transposes | g3 | count+posrec
  mergeA<<<GA_T + 1 + GA_C, 256, 0, stream>>>(W1a, W1b, W2a, W2b,
                                              w1aT, w1bT, w2aT, w2bT,
                                              gf, W3a, b3a, W3b, b3b, g3,
                                              eix, deg, posrec, 2 * E);
  scan_kernel<<<1, 1024, 0, stream>>>(deg, rowst, N);

  // GEMM layer1 with the atomic-free scatter folded into its dispatch tail
  gemm_l1_scat<<<L1_GEMM + L1_SCAT, 256, 0, stream>>>(x, w1aT, b1a, w2aT, b2a,
                                                      hidb, N,
                                                      eix, rowst, posrec, adj, E);
  gemm_l2<<<2048, 256, 0, stream>>>(hidb, w1bT, b1b, w2bT, b2b, h1b, h28, N);

  // pure sigmoid stream right before gather (s8 L3-hot)
  sigmoid_fp8<<<4096, 256, 0, stream>>>(ef, (uint2*)s8, E * DD / 8);

  gather_fp8<<<(N + 3) / 4, 256, 0, stream>>>(x, h1b, h28, s8, (const u64*)adj,
                                              rowst, g3, (float*)d_out, N);
}